// Round 1
// baseline (2845.284 us; speedup 1.0000x reference)
//
#include <hip/hip_runtime.h>
#include <cmath>

// ---------------- constants ----------------
constexpr int BB    = 8;     // batch
constexpr int LS    = 57;    // spectra tokens
constexpr int LG    = 9;     // gaia tokens
constexpr int RS    = BB*LS; // 456
constexpr int RG    = BB*LG; // 72
constexpr int DM    = 512;   // d_model
constexpr int DPROJ = 2320;
constexpr int DIN   = 1024;
constexpr int NH    = 16;    // mamba heads
constexpr int HD    = 64;    // mamba headdim
constexpr int NLAY  = 10;

__device__ __forceinline__ float siluf(float x){ return x / (1.f + expf(-x)); }

// ---------------- tokenize ----------------
__global__ __launch_bounds__(512) void tokenize_k(
    const float* __restrict__ x, const float* __restrict__ w, const float* __restrict__ bias,
    float* __restrict__ out, int in_dim, int tok_dim, int ntok)
{
    int t = blockIdx.x, b = blockIdx.y, d = threadIdx.x;
    __shared__ float xv[64];
    if (d < tok_dim) {
        int idx = t*tok_dim + d;
        xv[d] = (idx < in_dim) ? x[(size_t)b*in_dim + idx] : 0.f;
    }
    __syncthreads();
    float acc = bias[d];
    for (int k=0;k<tok_dim;k++) acc += xv[k]*w[(size_t)k*DM + d];
    out[(size_t)(b*ntok + t)*DM + d] = acc;
}

// ---------------- generic f32 GEMM C = A(MxK) @ B(KxN), dual-stack ----------------
__global__ __launch_bounds__(256) void gemm_nn_dual(
    const float* __restrict__ A0, const float* __restrict__ B0, float* __restrict__ C0, int M0,
    const float* __restrict__ A1, const float* __restrict__ B1, float* __restrict__ C1, int M1,
    int N, int K)
{
    const int z = blockIdx.z;
    const float* A = z ? A1 : A0;
    const float* Bm = z ? B1 : B0;
    float* C = z ? C1 : C0;
    const int M = z ? M1 : M0;
    const int bm = blockIdx.y*64, bn = blockIdx.x*64;
    if (bm >= M) return;
    __shared__ float As[16][68];
    __shared__ float Bs[16][68];
    const int tid = threadIdx.x, tx = tid & 15, ty = tid >> 4;
    float acc[4][4] = {};
    for (int k0=0; k0<K; k0+=16) {
        #pragma unroll
        for (int i=0;i<4;i++){
            int m = (tid>>4) + i*16, kk = tid & 15;
            As[kk][m] = (bm+m < M) ? A[(size_t)(bm+m)*K + k0+kk] : 0.f;
        }
        #pragma unroll
        for (int i=0;i<4;i++){
            int kk = (tid>>6) + i*4, n = tid & 63;
            Bs[kk][n] = (bn+n < N) ? Bm[(size_t)(k0+kk)*N + bn+n] : 0.f;
        }
        __syncthreads();
        #pragma unroll
        for (int kk=0;kk<16;kk++){
            float4 av = *(const float4*)&As[kk][ty*4];
            float4 wv = *(const float4*)&Bs[kk][tx*4];
            float a[4] = {av.x,av.y,av.z,av.w};
            float w[4] = {wv.x,wv.y,wv.z,wv.w};
            #pragma unroll
            for (int i=0;i<4;i++)
                #pragma unroll
                for (int j=0;j<4;j++) acc[i][j] += a[i]*w[j];
        }
        __syncthreads();
    }
    #pragma unroll
    for (int i=0;i<4;i++){
        int m = bm + ty*4 + i;
        if (m < M){
            #pragma unroll
            for (int j=0;j<4;j++){
                int n = bn + tx*4 + j;
                if (n < N) C[(size_t)m*N + n] = acc[i][j];
            }
        }
    }
}

// ---------------- GEMM C = A(MxK) @ W(NxK)^T + bias (+res) ----------------
__global__ __launch_bounds__(256) void gemm_nt(
    const float* __restrict__ A, const float* __restrict__ W,
    const float* __restrict__ bias, const float* __restrict__ res,
    float* __restrict__ C, int M, int N, int K)
{
    const int bm = blockIdx.y*64, bn = blockIdx.x*64;
    if (bm >= M) return;
    __shared__ float As[16][68];
    __shared__ float Ws[16][68];
    const int tid = threadIdx.x, tx = tid & 15, ty = tid >> 4;
    float acc[4][4] = {};
    for (int k0=0; k0<K; k0+=16) {
        #pragma unroll
        for (int i=0;i<4;i++){
            int m = (tid>>4) + i*16, kk = tid & 15;
            As[kk][m] = (bm+m < M) ? A[(size_t)(bm+m)*K + k0+kk] : 0.f;
        }
        {
            int n = tid>>2, kb = (tid&3)*4;   // N assumed multiple of 64 (=512)
            const float4 wv = *(const float4*)(W + (size_t)(bn+n)*K + k0 + kb);
            Ws[kb+0][n]=wv.x; Ws[kb+1][n]=wv.y; Ws[kb+2][n]=wv.z; Ws[kb+3][n]=wv.w;
        }
        __syncthreads();
        #pragma unroll
        for (int kk=0;kk<16;kk++){
            float4 av = *(const float4*)&As[kk][ty*4];
            float4 wv = *(const float4*)&Ws[kk][tx*4];
            float a[4] = {av.x,av.y,av.z,av.w};
            float w[4] = {wv.x,wv.y,wv.z,wv.w};
            #pragma unroll
            for (int i=0;i<4;i++)
                #pragma unroll
                for (int j=0;j<4;j++) acc[i][j] += a[i]*w[j];
        }
        __syncthreads();
    }
    #pragma unroll
    for (int i=0;i<4;i++){
        int m = bm + ty*4 + i;
        if (m < M){
            #pragma unroll
            for (int j=0;j<4;j++){
                int n = bn + tx*4 + j;
                float v = acc[i][j];
                if (bias) v += bias[n];
                if (res)  v += res[(size_t)m*N + n];
                C[(size_t)m*N + n] = v;
            }
        }
    }
}

// ---------------- fused conv1d+silu+softplus+SSM scan, per (head,batch,stack) ----------------
// block: 256 threads. thread t: p = t>>2 (headdim row), ng = t&3 (32-wide n slice).
// conv computed per-thread with a register shift window; conv outputs shared via LDS.
__global__ __launch_bounds__(256) void mamba_scan(
    const float* __restrict__ zx_s, const float* __restrict__ zx_g,
    const float* __restrict__ cw_s, const float* __restrict__ cw_g,
    const float* __restrict__ cb_s, const float* __restrict__ cb_g,
    const float* __restrict__ dtb_s, const float* __restrict__ dtb_g,
    const float* __restrict__ al_s, const float* __restrict__ al_g,
    const float* __restrict__ Dw_s, const float* __restrict__ Dw_g,
    float* __restrict__ y_s, float* __restrict__ y_g)
{
    const int h = blockIdx.x, b = blockIdx.y, st = blockIdx.z;
    const float* zx  = st ? zx_g  : zx_s;
    const float* cw  = st ? cw_g  : cw_s;
    const float* cb  = st ? cb_g  : cb_s;
    const float* dtb = st ? dtb_g : dtb_s;
    const float* al  = st ? al_g  : al_s;
    const float* Dw  = st ? Dw_g  : Dw_s;
    float* y = st ? y_g : y_s;
    const int L = st ? LG : LS;

    const int t = threadIdx.x;
    __shared__ float conv[320];  // [0..63]=xh(head h), [64..191]=B, [192..319]=C

    // column slot A: c = t (0..255); slot B: c = 256+t for t<64
    const int cA  = t;
    const int chA = (cA < 64) ? (h*HD + cA) : (960 + cA);
    float wA[4]; float cbA;
    #pragma unroll
    for (int k=0;k<4;k++) wA[k] = cw[chA*4 + k];
    cbA = cb[chA];
    const bool hasB = (t < 64);
    int chB = 1216 + t;
    float wB[4] = {0,0,0,0}; float cbB = 0.f;
    if (hasB) {
        #pragma unroll
        for (int k=0;k<4;k++) wB[k] = cw[chB*4 + k];
        cbB = cb[chB];
    }

    const float Ah     = -expf(al[h]);
    const float dtbias = dtb[h];
    const float Dh     = Dw[h];

    const int p = t >> 2, ng = t & 3;
    float hst[32];
    #pragma unroll
    for (int j=0;j<32;j++) hst[j] = 0.f;

    float histA0=0.f, histA1=0.f, histA2=0.f;   // raw[l-3], raw[l-2], raw[l-1] for col A
    float histB0=0.f, histB1=0.f, histB2=0.f;

    for (int l=0; l<L; ++l) {
        const size_t rowbase = (size_t)(b*L + l)*DPROJ;
        const float rawA = zx[rowbase + 1024 + chA];
        float rawB = 0.f;
        if (hasB) rawB = zx[rowbase + 1024 + chB];
        const float dtraw = zx[rowbase + 2304 + h];

        // conv + silu (register shift window; left zero-pad handled by zero init)
        float accA = cbA + wA[0]*histA0 + wA[1]*histA1 + wA[2]*histA2 + wA[3]*rawA;
        conv[cA] = siluf(accA);
        histA0 = histA1; histA1 = histA2; histA2 = rawA;
        if (hasB) {
            float accB = cbB + wB[0]*histB0 + wB[1]*histB1 + wB[2]*histB2 + wB[3]*rawB;
            conv[256 + t] = siluf(accB);
            histB0 = histB1; histB1 = histB2; histB2 = rawB;
        }
        __syncthreads();

        // scan step
        float dtv = dtraw + dtbias;
        dtv = (dtv > 20.f) ? dtv : log1pf(expf(dtv));
        const float dA   = expf(dtv * Ah);
        const float xh   = conv[p];
        const float coef = dtv * xh;
        const float* Bv  = &conv[64  + ng*32];
        const float* Cv  = &conv[192 + ng*32];
        float ysum = 0.f;
        #pragma unroll
        for (int j=0;j<32;j++){
            hst[j] = dA*hst[j] + coef*Bv[j];
            ysum  += hst[j]*Cv[j];
        }
        ysum += __shfl_xor(ysum, 1, 64);
        ysum += __shfl_xor(ysum, 2, 64);
        if (ng == 0)
            y[(size_t)(b*L + l)*DIN + h*HD + p] = ysum + Dh*xh;
        __syncthreads();
    }
}

// ---------------- gated RMSNorm (both stacks in one grid) ----------------
__global__ __launch_bounds__(256) void gated_rmsnorm(
    const float* __restrict__ y_s, const float* __restrict__ zx_s, const float* __restrict__ nw_s, float* __restrict__ o_s,
    const float* __restrict__ y_g, const float* __restrict__ zx_g, const float* __restrict__ nw_g, float* __restrict__ o_g)
{
    int r = blockIdx.x, t = threadIdx.x;
    int st = (r >= RS);
    int row = st ? r - RS : r;
    const float* y  = (st ? y_g  : y_s)  + (size_t)row*DIN;
    const float* z  = (st ? zx_g : zx_s) + (size_t)row*DPROJ;   // z = first 1024 cols
    const float* nw = st ? nw_g : nw_s;
    float* o = (st ? o_g : o_s) + (size_t)row*DIN;

    float g[4]; float s2 = 0.f;
    #pragma unroll
    for (int i=0;i<4;i++){
        int idx = t + i*256;
        float gv = y[idx] * siluf(z[idx]);
        g[i] = gv; s2 += gv*gv;
    }
    #pragma unroll
    for (int o2=32;o2;o2>>=1) s2 += __shfl_xor(s2, o2, 64);
    __shared__ float red[4];
    if ((t & 63) == 0) red[t>>6] = s2;
    __syncthreads();
    float S2 = red[0]+red[1]+red[2]+red[3];
    float scale = rsqrtf(S2*(1.f/DIN) + 1e-5f);
    #pragma unroll
    for (int i=0;i<4;i++){
        int idx = t + i*256;
        o[idx] = g[i]*scale*nw[idx];
    }
}

// ---------------- LayerNorm rows ----------------
__global__ __launch_bounds__(256) void ln_rows(
    const float* __restrict__ x, const float* __restrict__ w, const float* __restrict__ b,
    float* __restrict__ out, int D)
{
    int r = blockIdx.x, t = threadIdx.x;
    const float* xr = x + (size_t)r*D;
    float s = 0.f, s2 = 0.f;
    for (int i=t;i<D;i+=256){ float v = xr[i]; s += v; s2 += v*v; }
    #pragma unroll
    for (int o=32;o;o>>=1){ s += __shfl_xor(s,o,64); s2 += __shfl_xor(s2,o,64); }
    __shared__ float red[8];
    if ((t & 63) == 0){ red[t>>6] = s; red[4+(t>>6)] = s2; }
    __syncthreads();
    float S  = red[0]+red[1]+red[2]+red[3];
    float S2 = red[4]+red[5]+red[6]+red[7];
    float mean = S/D;
    float var  = S2/D - mean*mean;
    float inv  = rsqrtf(var + 1e-5f);
    for (int i=t;i<D;i+=256)
        out[(size_t)r*D + i] = (xr[i]-mean)*inv*w[i] + b[i];
}

// ---------------- cross-attention core, per (head,batch) ----------------
template<int LQ, int LKV>
__global__ __launch_bounds__(64) void mha_attn(
    const float* __restrict__ qh, const float* __restrict__ kh,
    const float* __restrict__ vh, float* __restrict__ out)
{
    const int hh = blockIdx.x, b = blockIdx.y, t = threadIdx.x;
    __shared__ float ks[LKV*64], vs[LKV*64];
    for (int r=0;r<LKV;r++){
        ks[r*64+t] = kh[(size_t)(b*LKV+r)*DM + hh*64 + t];
        vs[r*64+t] = vh[(size_t)(b*LKV+r)*DM + hh*64 + t];
    }
    __syncthreads();
    if (t < LQ) {
        float q[64];
        const float* qr = qh + (size_t)(b*LQ+t)*DM + hh*64;
        #pragma unroll
        for (int d=0;d<64;d++) q[d] = qr[d];
        float sc[LKV]; float mx = -1e30f;
        #pragma unroll
        for (int j=0;j<LKV;j++){
            float s = 0.f;
            #pragma unroll
            for (int d=0;d<64;d++) s += q[d]*ks[j*64+d];
            s *= 0.125f;
            sc[j] = s; mx = fmaxf(mx, s);
        }
        float se = 0.f;
        #pragma unroll
        for (int j=0;j<LKV;j++){ sc[j] = expf(sc[j]-mx); se += sc[j]; }
        float inv = 1.f/se;
        float* orow = out + (size_t)(b*LQ+t)*DM + hh*64;
        #pragma unroll
        for (int d=0;d<64;d++){
            float o = 0.f;
            #pragma unroll
            for (int j=0;j<LKV;j++) o += sc[j]*vs[j*64+d];
            orow[d] = o*inv;
        }
    }
}

// ---------------- mean pool (concat) ----------------
__global__ __launch_bounds__(512) void meanpool(
    const float* __restrict__ xs, const float* __restrict__ xg, float* __restrict__ fused)
{
    int b = blockIdx.x, d = threadIdx.x;
    float s = 0.f;
    for (int l=0;l<LS;l++) s += xs[(size_t)(b*LS+l)*DM + d];
    fused[b*1024 + d] = s*(1.f/LS);
    float g = 0.f;
    for (int l=0;l<LG;l++) g += xg[(size_t)(b*LG+l)*DM + d];
    fused[b*1024 + 512 + d] = g*(1.f/LG);
}

// ---------------- classifier head ----------------
__global__ __launch_bounds__(64) void cls_head(
    const float* __restrict__ lnf, const float* __restrict__ w,
    const float* __restrict__ bias, float* __restrict__ out)
{
    int b = blockIdx.x, t = threadIdx.x;
    __shared__ float xr[1024];
    for (int i=t;i<1024;i+=64) xr[i] = lnf[b*1024+i];
    __syncthreads();
    if (t < 55){
        float a = bias[t];
        const float* wr = w + (size_t)t*1024;
        for (int k=0;k<1024;k++) a += xr[k]*wr[k];
        out[b*55 + t] = a;
    }
}

// ---------------- launch ----------------
extern "C" void kernel_launch(void* const* d_in, const int* in_sizes, int n_in,
                              void* d_out, int out_size, void* d_ws, size_t ws_size,
                              hipStream_t stream)
{
    (void)in_sizes; (void)n_in; (void)out_size; (void)ws_size;
    const float* x_spectra = (const float*)d_in[0];
    const float* x_gaia    = (const float*)d_in[1];
    const float* tok_w_s   = (const float*)d_in[2];
    const float* tok_b_s   = (const float*)d_in[3];
    const float* tok_w_g   = (const float*)d_in[4];
    const float* tok_b_g   = (const float*)d_in[5];
    const float* ms_Win    = (const float*)d_in[6];
    const float* ms_conv_w = (const float*)d_in[7];
    const float* ms_conv_b = (const float*)d_in[8];
    const float* ms_dtb    = (const float*)d_in[9];
    const float* ms_Alog   = (const float*)d_in[10];
    const float* ms_D      = (const float*)d_in[11];
    const float* ms_nw     = (const float*)d_in[12];
    const float* ms_Wout   = (const float*)d_in[13];
    const float* mg_Win    = (const float*)d_in[14];
    const float* mg_conv_w = (const float*)d_in[15];
    const float* mg_conv_b = (const float*)d_in[16];
    const float* mg_dtb    = (const float*)d_in[17];
    const float* mg_Alog   = (const float*)d_in[18];
    const float* mg_D      = (const float*)d_in[19];
    const float* mg_nw     = (const float*)d_in[20];
    const float* mg_Wout   = (const float*)d_in[21];
    const float* cas_ln_w  = (const float*)d_in[22];
    const float* cas_ln_b  = (const float*)d_in[23];
    const float* cas_in_w  = (const float*)d_in[24];
    const float* cas_in_b  = (const float*)d_in[25];
    const float* cas_out_w = (const float*)d_in[26];
    const float* cas_out_b = (const float*)d_in[27];
    const float* cag_ln_w  = (const float*)d_in[28];
    const float* cag_ln_b  = (const float*)d_in[29];
    const float* cag_in_w  = (const float*)d_in[30];
    const float* cag_in_b  = (const float*)d_in[31];
    const float* cag_out_w = (const float*)d_in[32];
    const float* cag_out_b = (const float*)d_in[33];
    const float* cls_ln_w  = (const float*)d_in[34];
    const float* cls_ln_b  = (const float*)d_in[35];
    const float* cls_w     = (const float*)d_in[36];
    const float* cls_b     = (const float*)d_in[37];

    float* p = (float*)d_ws;
    auto alloc = [&](size_t n){ float* r = p; p += n; return r; };
    float* xs       = alloc((size_t)RS*DM);
    float* xg       = alloc((size_t)RG*DM);
    float* zx_s     = alloc((size_t)RS*DPROJ);
    float* zx_g     = alloc((size_t)RG*DPROJ);
    float* y_s      = alloc((size_t)RS*DIN);
    float* y_g      = alloc((size_t)RG*DIN);
    float* yn_s     = alloc((size_t)RS*DIN);
    float* yn_g     = alloc((size_t)RG*DIN);
    float* lnbuf    = alloc((size_t)RS*DM);
    float* qh       = alloc((size_t)RS*DM);
    float* kh       = alloc((size_t)RS*DM);
    float* vh       = alloc((size_t)RS*DM);
    float* attn_out = alloc((size_t)RS*DM);
    float* fused    = alloc((size_t)BB*1024);
    float* lnf      = alloc((size_t)BB*1024);

    // tokenize
    tokenize_k<<<dim3(LS,BB), 512, 0, stream>>>(x_spectra, tok_w_s, tok_b_s, xs, 3647, 64, LS);
    tokenize_k<<<dim3(LG,BB), 512, 0, stream>>>(x_gaia,    tok_w_g, tok_b_g, xg, 18,   2,  LG);

    // mamba stacks (dual launches: z=0 spectra, z=1 gaia)
    for (int i=0;i<NLAY;i++){
        const float* Win_s  = ms_Win  + (size_t)i*DM*DPROJ;
        const float* Win_g  = mg_Win  + (size_t)i*DM*DPROJ;
        const float* cw_s   = ms_conv_w + (size_t)i*1280*4;
        const float* cw_g   = mg_conv_w + (size_t)i*1280*4;
        const float* cbv_s  = ms_conv_b + (size_t)i*1280;
        const float* cbv_g  = mg_conv_b + (size_t)i*1280;
        const float* dtb_s  = ms_dtb  + (size_t)i*NH;
        const float* dtb_g  = mg_dtb  + (size_t)i*NH;
        const float* al_s   = ms_Alog + (size_t)i*NH;
        const float* al_g   = mg_Alog + (size_t)i*NH;
        const float* Dw_s   = ms_D    + (size_t)i*NH;
        const float* Dw_g   = mg_D    + (size_t)i*NH;
        const float* nw_s   = ms_nw   + (size_t)i*DIN;
        const float* nw_g   = mg_nw   + (size_t)i*DIN;
        const float* Wout_s = ms_Wout + (size_t)i*DIN*DM;
        const float* Wout_g = mg_Wout + (size_t)i*DIN*DM;

        gemm_nn_dual<<<dim3((DPROJ+63)/64, (RS+63)/64, 2), 256, 0, stream>>>(
            xs, Win_s, zx_s, RS,  xg, Win_g, zx_g, RG,  DPROJ, DM);
        mamba_scan<<<dim3(NH, BB, 2), 256, 0, stream>>>(
            zx_s, zx_g, cw_s, cw_g, cbv_s, cbv_g, dtb_s, dtb_g, al_s, al_g, Dw_s, Dw_g, y_s, y_g);
        gated_rmsnorm<<<dim3(RS+RG), 256, 0, stream>>>(
            y_s, zx_s, nw_s, yn_s,  y_g, zx_g, nw_g, yn_g);
        gemm_nn_dual<<<dim3(DM/64, (RS+63)/64, 2), 256, 0, stream>>>(
            yn_s, Wout_s, xs, RS,  yn_g, Wout_g, xg, RG,  DM, DIN);
    }

    // cross-attention: xs = xs + MHA(LN(xs), xg)
    ln_rows<<<dim3(RS), 256, 0, stream>>>(xs, cas_ln_w, cas_ln_b, lnbuf, DM);
    gemm_nt<<<dim3(DM/64, (RS+63)/64), 256, 0, stream>>>(lnbuf, cas_in_w,            cas_in_b,      nullptr, qh, RS, DM, DM);
    gemm_nt<<<dim3(DM/64, (RG+63)/64), 256, 0, stream>>>(xg,    cas_in_w +  512*512, cas_in_b+512,  nullptr, kh, RG, DM, DM);
    gemm_nt<<<dim3(DM/64, (RG+63)/64), 256, 0, stream>>>(xg,    cas_in_w + 1024*512, cas_in_b+1024, nullptr, vh, RG, DM, DM);
    mha_attn<LS,LG><<<dim3(8,BB), 64, 0, stream>>>(qh, kh, vh, attn_out);
    gemm_nt<<<dim3(DM/64, (RS+63)/64), 256, 0, stream>>>(attn_out, cas_out_w, cas_out_b, xs, xs, RS, DM, DM);

    // cross-attention: xg = xg + MHA(LN(xg), xs_updated)
    ln_rows<<<dim3(RG), 256, 0, stream>>>(xg, cag_ln_w, cag_ln_b, lnbuf, DM);
    gemm_nt<<<dim3(DM/64, (RG+63)/64), 256, 0, stream>>>(lnbuf, cag_in_w,            cag_in_b,      nullptr, qh, RG, DM, DM);
    gemm_nt<<<dim3(DM/64, (RS+63)/64), 256, 0, stream>>>(xs,    cag_in_w +  512*512, cag_in_b+512,  nullptr, kh, RS, DM, DM);
    gemm_nt<<<dim3(DM/64, (RS+63)/64), 256, 0, stream>>>(xs,    cag_in_w + 1024*512, cag_in_b+1024, nullptr, vh, RS, DM, DM);
    mha_attn<LG,LS><<<dim3(8,BB), 64, 0, stream>>>(qh, kh, vh, attn_out);
    gemm_nt<<<dim3(DM/64, (RG+63)/64), 256, 0, stream>>>(attn_out, cag_out_w, cag_out_b, xg, xg, RG, DM, DM);

    // head
    meanpool<<<dim3(BB), 512, 0, stream>>>(xs, xg, fused);
    ln_rows<<<dim3(BB), 256, 0, stream>>>(fused, cls_ln_w, cls_ln_b, lnf, 1024);
    cls_head<<<dim3(BB), 64, 0, stream>>>(lnf, cls_w, cls_b, (float*)d_out);
}

// Round 2
// 1820.714 us; speedup vs baseline: 1.5627x; 1.5627x over previous
//
#include <hip/hip_runtime.h>
#include <cmath>

// ---------------- constants ----------------
constexpr int BB    = 8;     // batch
constexpr int LS    = 57;    // spectra tokens
constexpr int LG    = 9;     // gaia tokens
constexpr int RS    = BB*LS; // 456
constexpr int RG    = BB*LG; // 72
constexpr int DM    = 512;   // d_model
constexpr int DPROJ = 2320;
constexpr int DIN   = 1024;
constexpr int NH    = 16;    // mamba heads
constexpr int HD    = 64;    // mamba headdim
constexpr int NLAY  = 10;

__device__ __forceinline__ float siluf(float x){ return x / (1.f + expf(-x)); }

// ---------------- tokenize ----------------
__global__ __launch_bounds__(512) void tokenize_k(
    const float* __restrict__ x, const float* __restrict__ w, const float* __restrict__ bias,
    float* __restrict__ out, int in_dim, int tok_dim, int ntok)
{
    int t = blockIdx.x, b = blockIdx.y, d = threadIdx.x;
    __shared__ float xv[64];
    if (d < tok_dim) {
        int idx = t*tok_dim + d;
        xv[d] = (idx < in_dim) ? x[(size_t)b*in_dim + idx] : 0.f;
    }
    __syncthreads();
    float acc = bias[d];
    for (int k=0;k<tok_dim;k++) acc += xv[k]*w[(size_t)k*DM + d];
    out[(size_t)(b*ntok + t)*DM + d] = acc;
}

// ---------------- double-buffered f32 GEMM ----------------
// C[M][N] = A[M][K] @ B   (TB=false: B is [K][N] row-major; TB=true: B is [N][K])
// BM=64 fixed, BN/TN template. 256 threads, per-thread 4 x TN outputs.
// One barrier per K-step; global prefetch of tile t+1 overlaps compute of tile t.
struct GemmJob {
    const float* A; const float* B; const float* bias; const float* res; float* C; int M;
};

template<int BN, int TN, bool TB>
__global__ __launch_bounds__(256) void gemm_tile(GemmJob j0, GemmJob j1, GemmJob j2, int N, int K)
{
    GemmJob jb = (blockIdx.z==0) ? j0 : (blockIdx.z==1 ? j1 : j2);
    const int bm = blockIdx.y*64, bn = blockIdx.x*BN;
    const int M = jb.M;
    if (bm >= M) return;
    __shared__ float As[2][16][68];
    __shared__ float Bs[2][16][BN+4];
    const int tid = threadIdx.x, tx = tid & 15, ty = tid >> 4;
    const float* __restrict__ A  = jb.A;
    const float* __restrict__ Bm = jb.B;
    float acc[4][TN] = {};

    const int arow = tid>>2, akb = (tid&3)*4;
    float4 ra, rb0, rb1;

    auto zero4 = [](){ float4 z; z.x=0.f; z.y=0.f; z.z=0.f; z.w=0.f; return z; };

    auto loadT = [&](int k0){
        ra = (bm+arow < M) ? *(const float4*)(A + (size_t)(bm+arow)*K + k0 + akb) : zero4();
        if constexpr (!TB) {
            const int kr = tid>>4, c4 = (tid&15)*4;
            rb0 = (bn+c4 < N) ? *(const float4*)(Bm + (size_t)(k0+kr)*N + bn + c4) : zero4();
            if constexpr (TN==8)
                rb1 = (bn+64+c4 < N) ? *(const float4*)(Bm + (size_t)(k0+kr)*N + bn + 64 + c4) : zero4();
        } else {
            const int nr = tid>>2, kb = (tid&3)*4;
            rb0 = (bn+nr < N) ? *(const float4*)(Bm + (size_t)(bn+nr)*K + k0 + kb) : zero4();
        }
    };
    auto storeT = [&](int buf){
        As[buf][akb+0][arow] = ra.x;
        As[buf][akb+1][arow] = ra.y;
        As[buf][akb+2][arow] = ra.z;
        As[buf][akb+3][arow] = ra.w;
        if constexpr (!TB) {
            const int kr = tid>>4, c4 = (tid&15)*4;
            *(float4*)&Bs[buf][kr][c4] = rb0;
            if constexpr (TN==8) *(float4*)&Bs[buf][kr][64+c4] = rb1;
        } else {
            const int nr = tid>>2, kb = (tid&3)*4;
            Bs[buf][kb+0][nr] = rb0.x;
            Bs[buf][kb+1][nr] = rb0.y;
            Bs[buf][kb+2][nr] = rb0.z;
            Bs[buf][kb+3][nr] = rb0.w;
        }
    };

    const int nk = K/16;
    loadT(0);
    storeT(0);
    __syncthreads();
    for (int t=0; t<nk; ++t){
        const int cur = t & 1;
        if (t+1 < nk) loadT((t+1)*16);     // prefetch next tile into regs
        #pragma unroll
        for (int kk=0; kk<16; ++kk){
            float4 av = *(const float4*)&As[cur][kk][ty*4];
            float a[4] = {av.x, av.y, av.z, av.w};
            float b[TN];
            #pragma unroll
            for (int g=0; g<TN/4; ++g){
                float4 bv = *(const float4*)&Bs[cur][kk][tx*TN + g*4];
                b[g*4+0]=bv.x; b[g*4+1]=bv.y; b[g*4+2]=bv.z; b[g*4+3]=bv.w;
            }
            #pragma unroll
            for (int i=0;i<4;i++)
                #pragma unroll
                for (int j=0;j<TN;j++) acc[i][j] = fmaf(a[i], b[j], acc[i][j]);
        }
        if (t+1 < nk) storeT(cur^1);       // regs -> other LDS buffer
        __syncthreads();
    }

    #pragma unroll
    for (int i=0;i<4;i++){
        int m = bm + ty*4 + i;
        if (m < M){
            #pragma unroll
            for (int j=0;j<TN;j++){
                int n = bn + tx*TN + j;
                if (n < N){
                    float v = acc[i][j];
                    if (jb.bias) v += jb.bias[n];
                    if (jb.res)  v += jb.res[(size_t)m*N + n];
                    jb.C[(size_t)m*N + n] = v;
                }
            }
        }
    }
}

// ---------------- fused conv1d+silu+softplus+SSM scan, per (head,batch,stack) ----------------
// 1 barrier/step (double-buffered conv LDS) + software prefetch of next row.
__global__ __launch_bounds__(256) void mamba_scan(
    const float* __restrict__ zx_s, const float* __restrict__ zx_g,
    const float* __restrict__ cw_s, const float* __restrict__ cw_g,
    const float* __restrict__ cb_s, const float* __restrict__ cb_g,
    const float* __restrict__ dtb_s, const float* __restrict__ dtb_g,
    const float* __restrict__ al_s, const float* __restrict__ al_g,
    const float* __restrict__ Dw_s, const float* __restrict__ Dw_g,
    float* __restrict__ y_s, float* __restrict__ y_g)
{
    const int h = blockIdx.x, b = blockIdx.y, st = blockIdx.z;
    const float* zx  = st ? zx_g  : zx_s;
    const float* cw  = st ? cw_g  : cw_s;
    const float* cb  = st ? cb_g  : cb_s;
    const float* dtb = st ? dtb_g : dtb_s;
    const float* al  = st ? al_g  : al_s;
    const float* Dw  = st ? Dw_g  : Dw_s;
    float* y = st ? y_g : y_s;
    const int L = st ? LG : LS;

    const int t = threadIdx.x;
    __shared__ float conv[2][320];  // [0..63]=xh(head h), [64..191]=B, [192..319]=C

    const int cA  = t;
    const int chA = (cA < 64) ? (h*HD + cA) : (960 + cA);
    float wA[4]; float cbA;
    #pragma unroll
    for (int k=0;k<4;k++) wA[k] = cw[chA*4 + k];
    cbA = cb[chA];
    const bool hasB = (t < 64);
    int chB = 1216 + t;
    float wB[4] = {0,0,0,0}; float cbB = 0.f;
    if (hasB) {
        #pragma unroll
        for (int k=0;k<4;k++) wB[k] = cw[chB*4 + k];
        cbB = cb[chB];
    }

    const float Ah     = -expf(al[h]);
    const float dtbias = dtb[h];
    const float Dh     = Dw[h];

    const int p = t >> 2, ng = t & 3;
    float hst[32];
    #pragma unroll
    for (int j=0;j<32;j++) hst[j] = 0.f;

    float histA0=0.f, histA1=0.f, histA2=0.f;
    float histB0=0.f, histB1=0.f, histB2=0.f;

    // prologue load row 0
    float rawA, rawB = 0.f, dtraw;
    {
        const size_t rowbase = (size_t)(b*L + 0)*DPROJ;
        rawA = zx[rowbase + 1024 + chA];
        if (hasB) rawB = zx[rowbase + 1024 + chB];
        dtraw = zx[rowbase + 2304 + h];
    }

    for (int l=0; l<L; ++l) {
        // prefetch next row
        float nA = 0.f, nB = 0.f, nD = 0.f;
        if (l+1 < L) {
            const size_t rowbase = (size_t)(b*L + l+1)*DPROJ;
            nA = zx[rowbase + 1024 + chA];
            if (hasB) nB = zx[rowbase + 1024 + chB];
            nD = zx[rowbase + 2304 + h];
        }
        const int cbuf = l & 1;

        // conv + silu (register shift window)
        float accA = cbA + wA[0]*histA0 + wA[1]*histA1 + wA[2]*histA2 + wA[3]*rawA;
        conv[cbuf][cA] = siluf(accA);
        histA0 = histA1; histA1 = histA2; histA2 = rawA;
        if (hasB) {
            float accB = cbB + wB[0]*histB0 + wB[1]*histB1 + wB[2]*histB2 + wB[3]*rawB;
            conv[cbuf][256 + t] = siluf(accB);
            histB0 = histB1; histB1 = histB2; histB2 = rawB;
        }
        __syncthreads();

        // scan step
        float dtv = dtraw + dtbias;
        dtv = (dtv > 20.f) ? dtv : log1pf(expf(dtv));
        const float dA   = expf(dtv * Ah);
        const float xh   = conv[cbuf][p];
        const float coef = dtv * xh;
        const float* Bv  = &conv[cbuf][64  + ng*32];
        const float* Cv  = &conv[cbuf][192 + ng*32];
        float ysum = 0.f;
        #pragma unroll
        for (int j=0;j<32;j++){
            hst[j] = dA*hst[j] + coef*Bv[j];
            ysum  += hst[j]*Cv[j];
        }
        ysum += __shfl_xor(ysum, 1, 64);
        ysum += __shfl_xor(ysum, 2, 64);
        if (ng == 0)
            y[(size_t)(b*L + l)*DIN + h*HD + p] = ysum + Dh*xh;

        rawA = nA; rawB = nB; dtraw = nD;
    }
}

// ---------------- gated RMSNorm (both stacks in one grid) ----------------
__global__ __launch_bounds__(256) void gated_rmsnorm(
    const float* __restrict__ y_s, const float* __restrict__ zx_s, const float* __restrict__ nw_s, float* __restrict__ o_s,
    const float* __restrict__ y_g, const float* __restrict__ zx_g, const float* __restrict__ nw_g, float* __restrict__ o_g)
{
    int r = blockIdx.x, t = threadIdx.x;
    int st = (r >= RS);
    int row = st ? r - RS : r;
    const float* y  = (st ? y_g  : y_s)  + (size_t)row*DIN;
    const float* z  = (st ? zx_g : zx_s) + (size_t)row*DPROJ;
    const float* nw = st ? nw_g : nw_s;
    float* o = (st ? o_g : o_s) + (size_t)row*DIN;

    float g[4]; float s2 = 0.f;
    #pragma unroll
    for (int i=0;i<4;i++){
        int idx = t + i*256;
        float gv = y[idx] * siluf(z[idx]);
        g[i] = gv; s2 += gv*gv;
    }
    #pragma unroll
    for (int o2=32;o2;o2>>=1) s2 += __shfl_xor(s2, o2, 64);
    __shared__ float red[4];
    if ((t & 63) == 0) red[t>>6] = s2;
    __syncthreads();
    float S2 = red[0]+red[1]+red[2]+red[3];
    float scale = rsqrtf(S2*(1.f/DIN) + 1e-5f);
    #pragma unroll
    for (int i=0;i<4;i++){
        int idx = t + i*256;
        o[idx] = g[i]*scale*nw[idx];
    }
}

// ---------------- LayerNorm rows ----------------
__global__ __launch_bounds__(256) void ln_rows(
    const float* __restrict__ x, const float* __restrict__ w, const float* __restrict__ b,
    float* __restrict__ out, int D)
{
    int r = blockIdx.x, t = threadIdx.x;
    const float* xr = x + (size_t)r*D;
    float s = 0.f, s2 = 0.f;
    for (int i=t;i<D;i+=256){ float v = xr[i]; s += v; s2 += v*v; }
    #pragma unroll
    for (int o=32;o;o>>=1){ s += __shfl_xor(s,o,64); s2 += __shfl_xor(s2,o,64); }
    __shared__ float red[8];
    if ((t & 63) == 0){ red[t>>6] = s; red[4+(t>>6)] = s2; }
    __syncthreads();
    float S  = red[0]+red[1]+red[2]+red[3];
    float S2 = red[4]+red[5]+red[6]+red[7];
    float mean = S/D;
    float var  = S2/D - mean*mean;
    float inv  = rsqrtf(var + 1e-5f);
    for (int i=t;i<D;i+=256)
        out[(size_t)r*D + i] = (xr[i]-mean)*inv*w[i] + b[i];
}

// ---------------- cross-attention core, per (head,batch) ----------------
template<int LQ, int LKV>
__global__ __launch_bounds__(64) void mha_attn(
    const float* __restrict__ qh, const float* __restrict__ kh,
    const float* __restrict__ vh, float* __restrict__ out)
{
    const int hh = blockIdx.x, b = blockIdx.y, t = threadIdx.x;
    __shared__ float ks[LKV*64], vs[LKV*64];
    for (int r=0;r<LKV;r++){
        ks[r*64+t] = kh[(size_t)(b*LKV+r)*DM + hh*64 + t];
        vs[r*64+t] = vh[(size_t)(b*LKV+r)*DM + hh*64 + t];
    }
    __syncthreads();
    if (t < LQ) {
        float q[64];
        const float* qr = qh + (size_t)(b*LQ+t)*DM + hh*64;
        #pragma unroll
        for (int d=0;d<64;d++) q[d] = qr[d];
        float sc[LKV]; float mx = -1e30f;
        #pragma unroll
        for (int j=0;j<LKV;j++){
            float s = 0.f;
            #pragma unroll
            for (int d=0;d<64;d++) s += q[d]*ks[j*64+d];
            s *= 0.125f;
            sc[j] = s; mx = fmaxf(mx, s);
        }
        float se = 0.f;
        #pragma unroll
        for (int j=0;j<LKV;j++){ sc[j] = expf(sc[j]-mx); se += sc[j]; }
        float inv = 1.f/se;
        float* orow = out + (size_t)(b*LQ+t)*DM + hh*64;
        #pragma unroll
        for (int d=0;d<64;d++){
            float o = 0.f;
            #pragma unroll
            for (int j=0;j<LKV;j++) o += sc[j]*vs[j*64+d];
            orow[d] = o*inv;
        }
    }
}

// ---------------- mean pool (concat) ----------------
__global__ __launch_bounds__(512) void meanpool(
    const float* __restrict__ xs, const float* __restrict__ xg, float* __restrict__ fused)
{
    int b = blockIdx.x, d = threadIdx.x;
    float s = 0.f;
    for (int l=0;l<LS;l++) s += xs[(size_t)(b*LS+l)*DM + d];
    fused[b*1024 + d] = s*(1.f/LS);
    float g = 0.f;
    for (int l=0;l<LG;l++) g += xg[(size_t)(b*LG+l)*DM + d];
    fused[b*1024 + 512 + d] = g*(1.f/LG);
}

// ---------------- classifier head ----------------
__global__ __launch_bounds__(64) void cls_head(
    const float* __restrict__ lnf, const float* __restrict__ w,
    const float* __restrict__ bias, float* __restrict__ out)
{
    int b = blockIdx.x, t = threadIdx.x;
    __shared__ float xr[1024];
    for (int i=t;i<1024;i+=64) xr[i] = lnf[b*1024+i];
    __syncthreads();
    if (t < 55){
        float a = bias[t];
        const float* wr = w + (size_t)t*1024;
        for (int k=0;k<1024;k++) a += xr[k]*wr[k];
        out[b*55 + t] = a;
    }
}

// ---------------- launch ----------------
extern "C" void kernel_launch(void* const* d_in, const int* in_sizes, int n_in,
                              void* d_out, int out_size, void* d_ws, size_t ws_size,
                              hipStream_t stream)
{
    (void)in_sizes; (void)n_in; (void)out_size; (void)ws_size;
    const float* x_spectra = (const float*)d_in[0];
    const float* x_gaia    = (const float*)d_in[1];
    const float* tok_w_s   = (const float*)d_in[2];
    const float* tok_b_s   = (const float*)d_in[3];
    const float* tok_w_g   = (const float*)d_in[4];
    const float* tok_b_g   = (const float*)d_in[5];
    const float* ms_Win    = (const float*)d_in[6];
    const float* ms_conv_w = (const float*)d_in[7];
    const float* ms_conv_b = (const float*)d_in[8];
    const float* ms_dtb    = (const float*)d_in[9];
    const float* ms_Alog   = (const float*)d_in[10];
    const float* ms_D      = (const float*)d_in[11];
    const float* ms_nw     = (const float*)d_in[12];
    const float* ms_Wout   = (const float*)d_in[13];
    const float* mg_Win    = (const float*)d_in[14];
    const float* mg_conv_w = (const float*)d_in[15];
    const float* mg_conv_b = (const float*)d_in[16];
    const float* mg_dtb    = (const float*)d_in[17];
    const float* mg_Alog   = (const float*)d_in[18];
    const float* mg_D      = (const float*)d_in[19];
    const float* mg_nw     = (const float*)d_in[20];
    const float* mg_Wout   = (const float*)d_in[21];
    const float* cas_ln_w  = (const float*)d_in[22];
    const float* cas_ln_b  = (const float*)d_in[23];
    const float* cas_in_w  = (const float*)d_in[24];
    const float* cas_in_b  = (const float*)d_in[25];
    const float* cas_out_w = (const float*)d_in[26];
    const float* cas_out_b = (const float*)d_in[27];
    const float* cag_ln_w  = (const float*)d_in[28];
    const float* cag_ln_b  = (const float*)d_in[29];
    const float* cag_in_w  = (const float*)d_in[30];
    const float* cag_in_b  = (const float*)d_in[31];
    const float* cag_out_w = (const float*)d_in[32];
    const float* cag_out_b = (const float*)d_in[33];
    const float* cls_ln_w  = (const float*)d_in[34];
    const float* cls_ln_b  = (const float*)d_in[35];
    const float* cls_w     = (const float*)d_in[36];
    const float* cls_b     = (const float*)d_in[37];

    float* p = (float*)d_ws;
    auto alloc = [&](size_t n){ float* r = p; p += n; return r; };
    float* xs       = alloc((size_t)RS*DM);
    float* xg       = alloc((size_t)RG*DM);
    float* zx_s     = alloc((size_t)RS*DPROJ);
    float* zx_g     = alloc((size_t)RG*DPROJ);
    float* y_s      = alloc((size_t)RS*DIN);
    float* y_g      = alloc((size_t)RG*DIN);
    float* yn_s     = alloc((size_t)RS*DIN);
    float* yn_g     = alloc((size_t)RG*DIN);
    float* lnbuf    = alloc((size_t)RS*DM);
    float* qh       = alloc((size_t)RS*DM);
    float* kh       = alloc((size_t)RS*DM);
    float* vh       = alloc((size_t)RS*DM);
    float* attn_out = alloc((size_t)RS*DM);
    float* fused    = alloc((size_t)BB*1024);
    float* lnf      = alloc((size_t)BB*1024);

    // tokenize
    tokenize_k<<<dim3(LS,BB), 512, 0, stream>>>(x_spectra, tok_w_s, tok_b_s, xs, 3647, 64, LS);
    tokenize_k<<<dim3(LG,BB), 512, 0, stream>>>(x_gaia,    tok_w_g, tok_b_g, xg, 18,   2,  LG);

    // mamba stacks (dual launches: z=0 spectra, z=1 gaia)
    for (int i=0;i<NLAY;i++){
        const float* Win_s  = ms_Win  + (size_t)i*DM*DPROJ;
        const float* Win_g  = mg_Win  + (size_t)i*DM*DPROJ;
        const float* cw_s   = ms_conv_w + (size_t)i*1280*4;
        const float* cw_g   = mg_conv_w + (size_t)i*1280*4;
        const float* cbv_s  = ms_conv_b + (size_t)i*1280;
        const float* cbv_g  = mg_conv_b + (size_t)i*1280;
        const float* dtb_s  = ms_dtb  + (size_t)i*NH;
        const float* dtb_g  = mg_dtb  + (size_t)i*NH;
        const float* al_s   = ms_Alog + (size_t)i*NH;
        const float* al_g   = mg_Alog + (size_t)i*NH;
        const float* Dw_s   = ms_D    + (size_t)i*NH;
        const float* Dw_g   = mg_D    + (size_t)i*NH;
        const float* nw_s   = ms_nw   + (size_t)i*DIN;
        const float* nw_g   = mg_nw   + (size_t)i*DIN;
        const float* Wout_s = ms_Wout + (size_t)i*DIN*DM;
        const float* Wout_g = mg_Wout + (size_t)i*DIN*DM;

        GemmJob inS{xs, Win_s, nullptr, nullptr, zx_s, RS};
        GemmJob inG{xg, Win_g, nullptr, nullptr, zx_g, RG};
        gemm_tile<128,8,false><<<dim3((DPROJ+127)/128, 8, 2), 256, 0, stream>>>(
            inS, inG, inG, DPROJ, DM);

        mamba_scan<<<dim3(NH, BB, 2), 256, 0, stream>>>(
            zx_s, zx_g, cw_s, cw_g, cbv_s, cbv_g, dtb_s, dtb_g, al_s, al_g, Dw_s, Dw_g, y_s, y_g);

        gated_rmsnorm<<<dim3(RS+RG), 256, 0, stream>>>(
            y_s, zx_s, nw_s, yn_s,  y_g, zx_g, nw_g, yn_g);

        GemmJob outS{yn_s, Wout_s, nullptr, nullptr, xs, RS};
        GemmJob outG{yn_g, Wout_g, nullptr, nullptr, xg, RG};
        gemm_tile<64,4,false><<<dim3(DM/64, 8, 2), 256, 0, stream>>>(
            outS, outG, outG, DM, DIN);
    }

    // cross-attention: xs = xs + MHA(LN(xs), xg)
    {
        ln_rows<<<dim3(RS), 256, 0, stream>>>(xs, cas_ln_w, cas_ln_b, lnbuf, DM);
        GemmJob jq{lnbuf, cas_in_w,            cas_in_b,      nullptr, qh, RS};
        GemmJob jk{xg,    cas_in_w +  512*512, cas_in_b+512,  nullptr, kh, RG};
        GemmJob jv{xg,    cas_in_w + 1024*512, cas_in_b+1024, nullptr, vh, RG};
        gemm_tile<64,4,true><<<dim3(DM/64, 8, 3), 256, 0, stream>>>(jq, jk, jv, DM, DM);
        mha_attn<LS,LG><<<dim3(8,BB), 64, 0, stream>>>(qh, kh, vh, attn_out);
        GemmJob jo{attn_out, cas_out_w, cas_out_b, xs, xs, RS};
        gemm_tile<64,4,true><<<dim3(DM/64, 8, 1), 256, 0, stream>>>(jo, jo, jo, DM, DM);
    }

    // cross-attention: xg = xg + MHA(LN(xg), xs_updated)
    {
        ln_rows<<<dim3(RG), 256, 0, stream>>>(xg, cag_ln_w, cag_ln_b, lnbuf, DM);
        GemmJob jq{lnbuf, cag_in_w,            cag_in_b,      nullptr, qh, RG};
        GemmJob jk{xs,    cag_in_w +  512*512, cag_in_b+512,  nullptr, kh, RS};
        GemmJob jv{xs,    cag_in_w + 1024*512, cag_in_b+1024, nullptr, vh, RS};
        gemm_tile<64,4,true><<<dim3(DM/64, 8, 3), 256, 0, stream>>>(jq, jk, jv, DM, DM);
        mha_attn<LG,LS><<<dim3(8,BB), 64, 0, stream>>>(qh, kh, vh, attn_out);
        GemmJob jo{attn_out, cag_out_w, cag_out_b, xg, xg, RG};
        gemm_tile<64,4,true><<<dim3(DM/64, 2, 1), 256, 0, stream>>>(jo, jo, jo, DM, DM);
    }

    // head
    meanpool<<<dim3(BB), 512, 0, stream>>>(xs, xg, fused);
    ln_rows<<<dim3(BB), 256, 0, stream>>>(fused, cls_ln_w, cls_ln_b, lnf, 1024);
    cls_head<<<dim3(BB), 64, 0, stream>>>(lnf, cls_w, cls_b, (float*)d_out);
}